// Round 1
// baseline (67.555 us; speedup 1.0000x reference)
//
#include <hip/hip_runtime.h>
#include <math.h>

// x: [512,64,64,1] f32, conv_w: [3,3,1,32] f32, conv_b: [32],
// dense_w: [32,10], dense_b: [10]; out: [512,10] f32 softmax.
//
// Algebraic collapse: conv -> global-mean-pool means we only need, per image,
// the 9 shifted-window sums S[k], all derivable from:
//   T (total), Rt (row 0 sum), Rb (row 63), Cl (col 0), Cr (col 63), 4 corners.
// logits[b,j] = (1/4096) * sum_k S[b,k] * M[k,j] + bias[j]
//   M[k,j] = sum_c sign(conv_w[k,c]) * dense_w[c,j]   (9x10, tiny)
//   bias[j] = sum_c conv_b[c]*dense_w[c,j] + dense_b[j]

__global__ __launch_bounds__(256) void binconv_fused(
    const float* __restrict__ x,
    const float* __restrict__ conv_w,
    const float* __restrict__ conv_b,
    const float* __restrict__ dense_w,
    const float* __restrict__ dense_b,
    float* __restrict__ out)
{
    const int b = blockIdx.x;
    const int tid = threadIdx.x;
    const float* img = x + (size_t)b * 4096;
    const float4* img4 = (const float4*)img;

    // Each thread loads 4 float4 (1024 float4 per 64x64 image).
    float tot = 0.f, top = 0.f, bot = 0.f, lef = 0.f, rig = 0.f;
#pragma unroll
    for (int it = 0; it < 4; ++it) {
        int i = it * 256 + tid;          // float4 index 0..1023
        float4 v = img4[i];
        float s4 = (v.x + v.y) + (v.z + v.w);
        int r  = i >> 4;                 // 16 float4 per row
        int c0 = (i & 15) << 2;          // starting column of this float4
        tot += s4;
        if (r == 0)   top += s4;
        if (r == 63)  bot += s4;
        if (c0 == 0)  lef += v.x;
        if (c0 == 60) rig += v.w;
    }

    // 64-lane wave butterfly reduction of the 5 partials.
#pragma unroll
    for (int off = 32; off; off >>= 1) {
        tot += __shfl_xor(tot, off);
        top += __shfl_xor(top, off);
        bot += __shfl_xor(bot, off);
        lef += __shfl_xor(lef, off);
        rig += __shfl_xor(rig, off);
    }

    __shared__ float wsum[4][5];   // 4 waves x 5 partials
    __shared__ float Msh[9][10];
    __shared__ float biassh[10];

    const int wave = tid >> 6, lane = tid & 63;
    if (lane == 0) {
        wsum[wave][0] = tot; wsum[wave][1] = top; wsum[wave][2] = bot;
        wsum[wave][3] = lef; wsum[wave][4] = rig;
    }

    // Tiny folded matrices, recomputed per block (L2-cached, free).
    if (tid < 90) {
        const int k = tid / 10, j = tid % 10;
        float m = 0.f;
#pragma unroll
        for (int c = 0; c < 32; ++c) {
            float w = conv_w[k * 32 + c];
            float s = (w >= 0.f) ? 1.f : -1.f;   // ste_sign: sign(0)=+1
            m += s * dense_w[c * 10 + j];
        }
        Msh[k][j] = m;
    } else if (tid < 100) {
        const int j = tid - 90;
        float bsum = dense_b[j];
        for (int c = 0; c < 32; ++c) bsum += conv_b[c] * dense_w[c * 10 + j];
        biassh[j] = bsum;
    }
    __syncthreads();

    if (tid == 0) {
        float T  = wsum[0][0] + wsum[1][0] + wsum[2][0] + wsum[3][0];
        float Rt = wsum[0][1] + wsum[1][1] + wsum[2][1] + wsum[3][1];
        float Rb = wsum[0][2] + wsum[1][2] + wsum[2][2] + wsum[3][2];
        float Cl = wsum[0][3] + wsum[1][3] + wsum[2][3] + wsum[3][3];
        float Cr = wsum[0][4] + wsum[1][4] + wsum[2][4] + wsum[3][4];
        const float x00 = img[0];
        const float x0e = img[63];
        const float xe0 = img[63 * 64];
        const float xee = img[63 * 64 + 63];

        // S[dh*3+dw]: window sum for tap (dh,dw); dh=0 drops row63, dh=2 drops
        // row0; dw=0 drops col63, dw=2 drops col0; add back corner if both.
        float S[9];
#pragma unroll
        for (int dh = 0; dh < 3; ++dh) {
#pragma unroll
            for (int dw = 0; dw < 3; ++dw) {
                float s = T;
                if (dh == 0) s -= Rb;
                if (dh == 2) s -= Rt;
                if (dw == 0) s -= Cr;
                if (dw == 2) s -= Cl;
                if (dh == 0 && dw == 0) s += xee;
                if (dh == 0 && dw == 2) s += xe0;
                if (dh == 2 && dw == 0) s += x0e;
                if (dh == 2 && dw == 2) s += x00;
                S[dh * 3 + dw] = s;
            }
        }

        float logits[10];
        float mx = -1e30f;
#pragma unroll
        for (int j = 0; j < 10; ++j) {
            float acc = 0.f;
#pragma unroll
            for (int k = 0; k < 9; ++k) acc += S[k] * Msh[k][j];
            acc = acc * (1.f / 4096.f) + biassh[j];
            logits[j] = acc;
            mx = fmaxf(mx, acc);
        }
        float se = 0.f;
#pragma unroll
        for (int j = 0; j < 10; ++j) { logits[j] = expf(logits[j] - mx); se += logits[j]; }
        const float inv = 1.f / se;
        float* o = out + b * 10;
#pragma unroll
        for (int j = 0; j < 10; ++j) o[j] = logits[j] * inv;
    }
}

extern "C" void kernel_launch(void* const* d_in, const int* in_sizes, int n_in,
                              void* d_out, int out_size, void* d_ws, size_t ws_size,
                              hipStream_t stream) {
    const float* x       = (const float*)d_in[0];
    const float* conv_w  = (const float*)d_in[1];
    const float* conv_b  = (const float*)d_in[2];
    const float* dense_w = (const float*)d_in[3];
    const float* dense_b = (const float*)d_in[4];
    float* out = (float*)d_out;
    binconv_fused<<<512, 256, 0, stream>>>(x, conv_w, conv_b, dense_w, dense_b, out);
}